// Round 3
// baseline (225.066 us; speedup 1.0000x reference)
//
#include <hip/hip_runtime.h>
#include <stdint.h>

#define NN 50000
#define NE 800000
#define D  128
#define CAP 64                            // bucket capacity per node (Poisson(16); P(deg>64)~1e-19)
#define OVF_CAP 131072

// ---------------- ws layout (int offsets) ----------------
// Counters init to -1 via 0xFF memset (slot = atomicAdd()+1). Buckets are
// UNINITIALIZED: gather masks tail entries with a uniform NaN-weight select,
// and garbage src indices are in-bounds via the 65536-row logical x table.
#define CNT_OFF     64                    // NN counters
#define OVF_CNT_OFF (CNT_OFF + NN)        // 50064
#define OVF_OFF     (OVF_CNT_OFF + 4)     // 50068: OVF_CAP pairs (dst, entry)
#define BKT_OFF     312320                // NN*CAP packed entries: (w_fp16<<16)|src
#define XH_OFF      (BKT_OFF + NN * CAP)  // 3512320: x as fp16 pairs; 65536 logical rows
#define WH_OFF      (XH_OFF + 65536 * (D / 2))      // 7706624: w1+w2 fp16
// total high-water: 7,723,008 ints = 30.9 MB (< 32.4 MB proven available)

#define HSTRIDE 136                       // LDS row stride in ushorts (272 B, 2-way banks = free)

// fused prep+fill block ranges
#define FILL_BLKS 782                     // ceil(NE/1024): 4 edges/thread for atomic MLP
#define PX_BLKS   6250                    // NN*D/1024
#define PW_BLKS   32

typedef _Float16 half8 __attribute__((ext_vector_type(8)));
typedef __attribute__((ext_vector_type(4))) float float4v;

// ---------------- dtype helpers ----------------
__device__ __forceinline__ float b2f(uint16_t u) {
    union { uint32_t u; float f; } v; v.u = ((uint32_t)u) << 16; return v.f;
}
__device__ __forceinline__ uint16_t f2b(float f) {
    union { float f; uint32_t u; } v; v.f = f;
    uint32_t r = v.u + 0x7fffu + ((v.u >> 16) & 1u);   // RNE
    return (uint16_t)(r >> 16);
}
__device__ __forceinline__ ushort f2h(float f) {
    union { _Float16 h; ushort u; } v; v.h = (_Float16)f; return v.u;   // v_cvt_f16_f32 (RNE)
}
__device__ __forceinline__ float h2f(ushort u) {
    union { ushort u; _Float16 h; } v; v.u = u; return (float)v.h;
}

// ---------------- per-block inline dtype probe (load-bearing; rounds 2-9) ----------------
__device__ __forceinline__ void block_probe(const uint16_t* __restrict__ xraw,
                                            const int* __restrict__ eraw,
                                            int* sflags) {
    int t = threadIdx.x;
    if (t < 64) {                                   // wave 0 only
        float v0 = b2f(xraw[2 * t]);
        float v1 = b2f(xraw[2 * t + 1]);
        int bad = (!(v0 > -1e4f && v0 < 1e4f)) || (!(v1 > -1e4f && v1 < 1e4f));
        unsigned long long bm = __ballot(bad);
        int nz = (t < 32) ? (eraw[2 * t + 1] != 0) : 0;
        unsigned long long im = __ballot(nz);
        if (t == 0) { sflags[0] = bm ? 1 : 0; sflags[1] = im ? 0 : 1; }
    }
    __syncthreads();
}

// ---------------- fused fill + prep_x + prep_w ----------------
__global__ __launch_bounds__(256) void prep_fill_kernel(
    const uint16_t* __restrict__ xraw,
    const int*      __restrict__ eraw,
    const uint16_t* __restrict__ ewraw,
    const uint16_t* __restrict__ w1raw,
    const uint16_t* __restrict__ w2raw,
    int* __restrict__ ws)
{
    __shared__ int sflags[2];
    block_probe(xraw, eraw, sflags);
    const int f32 = sflags[0], i64 = sflags[1];

    int bid = blockIdx.x;
    if (bid < FILL_BLKS) {
        // ---- edge fill: 4 edges/thread, issue-all-then-consume for MLP ----
        int ebase = bid * 1024 + threadIdx.x;
        int dst[4]; uint ent[4]; bool val[4];
        #pragma unroll
        for (int k = 0; k < 4; ++k) {
            int e  = ebase + k * 256;
            val[k] = (e < NE);
            int ec = val[k] ? e : 0;                 // clamp keeps loads in-bounds
            int s, d2;
            if (i64) {
                const long long* e64 = (const long long*)eraw;
                s  = (int)e64[ec];
                d2 = (int)e64[NE + ec];
            } else {
                s  = eraw[ec];
                d2 = eraw[NE + ec];
            }
            if ((unsigned)s >= NN || (unsigned)d2 >= NN) val[k] = false;
            uint w = f32 ? (uint)f2h(((const float*)ewraw)[ec])
                         : (uint)f2h(b2f(ewraw[ec]));
            dst[k] = d2;
            ent[k] = (w << 16) | (uint)(s & 0xffff);
        }
        // issue all atomics (independent -> 4 outstanding)
        int slot[4];
        #pragma unroll
        for (int k = 0; k < 4; ++k) {
            slot[k] = 0x7fffffff;
            if (val[k]) slot[k] = atomicAdd(ws + CNT_OFF + dst[k], 1) + 1;  // counter starts at -1
        }
        // consume
        #pragma unroll
        for (int k = 0; k < 4; ++k) {
            if (slot[k] < CAP) {
                ((uint*)(ws + BKT_OFF))[(size_t)dst[k] * CAP + slot[k]] = ent[k];
            } else if (slot[k] != 0x7fffffff) {
                int o = atomicAdd(ws + OVF_CNT_OFF, 1) + 1;  // starts at -1
                if (o < OVF_CAP) {
                    ws[OVF_OFF + 2 * o]     = dst[k];
                    ws[OVF_OFF + 2 * o + 1] = (int)ent[k];
                }
            }
        }
    } else if (bid < FILL_BLKS + PX_BLKS) {
        // ---- x -> fp16 table ----
        int i4 = ((bid - FILL_BLKS) * 256 + threadIdx.x) * 4;   // covers NN*D exactly
        ushort* dst = (ushort*)(ws + XH_OFF);
        if (f32) {
            float4 v = *(const float4*)((const float*)xraw + i4);
            ushort4 o; o.x = f2h(v.x); o.y = f2h(v.y); o.z = f2h(v.z); o.w = f2h(v.w);
            *(ushort4*)(dst + i4) = o;
        } else {
            ushort4 v = *(const ushort4*)(xraw + i4);
            ushort4 o; o.x = f2h(b2f(v.x)); o.y = f2h(b2f(v.y));
            o.z = f2h(b2f(v.z)); o.w = f2h(b2f(v.w));
            *(ushort4*)(dst + i4) = o;
        }
    } else {
        // ---- w1,w2 -> fp16 table ----
        int i4 = ((bid - FILL_BLKS - PX_BLKS) * 256 + threadIdx.x) * 4; // 0..32764
        const uint16_t* src = (i4 < 16384) ? w1raw : w2raw;
        int off = i4 & 16383;
        ushort* dst = (ushort*)(ws + WH_OFF);
        if (f32) {
            float4 v = *(const float4*)((const float*)src + off);
            ushort4 o; o.x = f2h(v.x); o.y = f2h(v.y); o.z = f2h(v.z); o.w = f2h(v.w);
            *(ushort4*)(dst + i4) = o;
        } else {
            ushort4 v = *(const ushort4*)(src + off);
            ushort4 o; o.x = f2h(b2f(v.x)); o.y = f2h(b2f(v.y));
            o.z = f2h(b2f(v.z)); o.w = f2h(b2f(v.w));
            *(ushort4*)(dst + i4) = o;
        }
    }
}

// ---------------- fused gather-max + MFMA MLP ----------------
// 16 nodes/block, 4 waves; wave gathers its 4 nodes INTERLEAVED: per step,
// phase A issues 4x4 uniform uint4 bucket-entry loads, phase B issues 4x16
// row gathers (64 outstanding), phase C consumes with packed fp16 mul/max.
// Tail masking is a uniform scalar select to NaN-weight bits (maxnum drops
// NaN), so buckets need NO pre-memset; garbage idx is in-bounds (65536 rows).
__global__ __launch_bounds__(256) void gmlp_kernel(
    const uint16_t* __restrict__ xraw,
    const int*      __restrict__ eraw,
    const uint16_t* __restrict__ b1raw,
    const uint16_t* __restrict__ b2raw,
    const uint16_t* __restrict__ epsraw,
    const int* __restrict__ ws,
    uint16_t* __restrict__ outraw)
{
    __shared__ int    sflags[2];
    __shared__ uint   tl[16 * (HSTRIDE / 2)];   // t tile, 68 uints/row
    __shared__ ushort hl[16 * HSTRIDE];         // hidden tile

    block_probe(xraw, eraw, sflags);
    const int f32 = sflags[0];

    const int tid  = threadIdx.x;
    const int wave = tid >> 6;
    const int lane = tid & 63;
    const int m    = lane & 15;
    const int quad = lane >> 4;
    const int node0 = blockIdx.x * 16;

    const ushort* w1h = (const ushort*)(ws + WH_OFF);
    const ushort* w2h = w1h + 16384;
    const uint*   xh  = (const uint*)(ws + XH_OFF);
    const char*   xhb = (const char*)xh;
    const uint*   bkt = (const uint*)(ws + BKT_OFF);
    const uint    lane4 = (uint)lane * 4;

    const float eps1 = 1.0f + (f32 ? ((const float*)epsraw)[0] : b2f(epsraw[0]));

    // per-node degree loads (4 independent)
    int deg[4], cnt[4], itn[4];
    #pragma unroll
    for (int j = 0; j < 4; ++j)
        deg[j] = ws[CNT_OFF + node0 + wave * 4 + j] + 1;     // counter = deg-1
    #pragma unroll
    for (int j = 0; j < 4; ++j) {
        cnt[j] = (deg[j] < CAP) ? deg[j] : CAP;
        itn[j] = (cnt[j] + 15) >> 4;
    }

    // packed fp16 running max, 4 regs/node (chain depth 4)
    uint mm[4][4];
    #pragma unroll
    for (int j = 0; j < 4; ++j)
        #pragma unroll
        for (int c = 0; c < 4; ++c) mm[j][c] = 0xFFFFFFFFu;  // fp16 NaN,NaN

    for (int step = 0; step < 4; ++step) {
        if (!((itn[0] > step) | (itn[1] > step) | (itn[2] > step) | (itn[3] > step)))
            break;                                           // uniform
        uint qq[4][16];
        uint vv[4][16];
        // phase A: issue uniform bucket-entry loads for all active nodes
        #pragma unroll
        for (int j = 0; j < 4; ++j) if (step < itn[j]) {
            const uint* brow = bkt + (size_t)(node0 + wave * 4 + j) * CAP + step * 16;
            #pragma unroll
            for (int q4 = 0; q4 < 4; ++q4)
                *(uint4*)&qq[j][q4 * 4] = *(const uint4*)(brow + q4 * 4);
        }
        // phase B: issue all row gathers (up to 64 outstanding)
        #pragma unroll
        for (int j = 0; j < 4; ++j) if (step < itn[j]) {
            #pragma unroll
            for (int u = 0; u < 16; ++u) {
                uint off = ((qq[j][u] & 0xffffu) << 8) + lane4;
                vv[j][u] = *(const uint*)(xhb + off);
            }
        }
        // phase C: consume
        #pragma unroll
        for (int j = 0; j < 4; ++j) if (step < itn[j]) {
            int cbase = step * 16;
            #pragma unroll
            for (int u = 0; u < 16; ++u) {
                uint e0 = qq[j][u];
                uint wb = ((cbase + u) < cnt[j]) ? e0 : 0xffffffffu;  // uniform sel -> NaN weight
                uint p;
                asm("v_pk_mul_f16 %0, %1, %2 op_sel:[0,1] op_sel_hi:[1,1]"
                    : "=v"(p) : "v"(vv[j][u]), "v"(wb));     // both halves * hi16(wb)
                asm("v_pk_max_f16 %0, %0, %1" : "+v"(mm[j][u & 3]) : "v"(p));
            }
        }
    }

    // reduce + epilogue per node
    #pragma unroll
    for (int j = 0; j < 4; ++j) {
        int nl = wave * 4 + j;
        int n  = node0 + nl;
        asm("v_pk_max_f16 %0, %0, %1" : "+v"(mm[j][0]) : "v"(mm[j][1]));
        asm("v_pk_max_f16 %0, %0, %1" : "+v"(mm[j][2]) : "v"(mm[j][3]));
        asm("v_pk_max_f16 %0, %0, %1" : "+v"(mm[j][0]) : "v"(mm[j][2]));
        float mx = h2f((ushort)(mm[j][0] & 0xffffu));
        float my = h2f((ushort)(mm[j][0] >> 16));

        // overflow edges (exactness insurance; statistically never taken)
        if (deg[j] > CAP) {
            int novf = ws[OVF_CNT_OFF] + 1;
            if (novf > OVF_CAP) novf = OVF_CAP;
            for (int o = 0; o < novf; ++o) {
                if (ws[OVF_OFF + 2 * o] == n) {
                    uint e0 = (uint)ws[OVF_OFF + 2 * o + 1];
                    uint v  = xh[(e0 & 0xffffu) * 64 + lane];
                    float w = h2f((ushort)(e0 >> 16));
                    mx = fmaxf(mx, h2f((ushort)(v & 0xffffu)) * w);
                    my = fmaxf(my, h2f((ushort)(v >> 16)) * w);
                }
            }
        }
        if (deg[j] == 0) { mx = 0.f; my = 0.f; }             // isolated node -> 0

        // self term from fp16 table (cache-hot)
        uint xv = xh[(size_t)n * 64 + lane];
        float t0 = eps1 * h2f((ushort)(xv & 0xffffu)) + mx;
        float t1 = eps1 * h2f((ushort)(xv >> 16)) + my;
        tl[nl * (HSTRIDE / 2) + lane] = (uint)f2h(t0) | ((uint)f2h(t1) << 16);
    }
    __syncthreads();

    // A frags from LDS t tile
    half8 a[4];
    {
        const ushort* arow = (const ushort*)tl + m * HSTRIDE + quad * 8;
        #pragma unroll
        for (int kb = 0; kb < 4; ++kb) a[kb] = *(const half8*)(arow + kb * 32);
    }

    // GEMM1 + bias + LeakyReLU -> hl
    #pragma unroll
    for (int t = 0; t < 2; ++t) {
        int ct = wave * 2 + t;
        float4v c = {0.f, 0.f, 0.f, 0.f};
        const ushort* brow = w1h + (size_t)(ct * 16 + m) * 128 + quad * 8;
        #pragma unroll
        for (int kb = 0; kb < 4; ++kb)
            c = __builtin_amdgcn_mfma_f32_16x16x32_f16(a[kb], *(const half8*)(brow + kb * 32), c, 0, 0, 0);
        float bias = f32 ? ((const float*)b1raw)[ct * 16 + m] : b2f(b1raw[ct * 16 + m]);
        #pragma unroll
        for (int r = 0; r < 4; ++r) {
            float v = c[r] + bias;
            v = (v >= 0.f) ? v : 0.01f * v;
            hl[(quad * 4 + r) * HSTRIDE + ct * 16 + m] = f2h(v);
        }
    }
    __syncthreads();

    // A frags for GEMM2 from hl
    half8 ah[4];
    {
        const ushort* hrow = hl + m * HSTRIDE + quad * 8;
        #pragma unroll
        for (int kb = 0; kb < 4; ++kb) ah[kb] = *(const half8*)(hrow + kb * 32);
    }

    // GEMM2 + bias -> out
    #pragma unroll
    for (int t = 0; t < 2; ++t) {
        int ct = wave * 2 + t;
        float4v c = {0.f, 0.f, 0.f, 0.f};
        const ushort* brow = w2h + (size_t)(ct * 16 + m) * 128 + quad * 8;
        #pragma unroll
        for (int kb = 0; kb < 4; ++kb)
            c = __builtin_amdgcn_mfma_f32_16x16x32_f16(ah[kb], *(const half8*)(brow + kb * 32), c, 0, 0, 0);
        float bias = f32 ? ((const float*)b2raw)[ct * 16 + m] : b2f(b2raw[ct * 16 + m]);
        #pragma unroll
        for (int r = 0; r < 4; ++r) {
            float v = c[r] + bias;
            size_t o = (size_t)(node0 + quad * 4 + r) * 128 + ct * 16 + m;
            if (f32) ((float*)outraw)[o] = v;
            else     outraw[o] = f2b(v);
        }
    }
}

// ================= host =================
extern "C" void kernel_launch(void* const* d_in, const int* in_sizes, int n_in,
                              void* d_out, int out_size, void* d_ws, size_t ws_size,
                              hipStream_t stream) {
    const uint16_t* x    = (const uint16_t*)d_in[0];
    const int*      eidx = (const int*)     d_in[1];
    const uint16_t* ew   = (const uint16_t*)d_in[2];
    const uint16_t* w1   = (const uint16_t*)d_in[3];
    const uint16_t* b1   = (const uint16_t*)d_in[4];
    const uint16_t* w2   = (const uint16_t*)d_in[5];
    const uint16_t* b2   = (const uint16_t*)d_in[6];
    const uint16_t* eps  = (const uint16_t*)d_in[7];
    uint16_t*       out  = (uint16_t*)d_out;
    int* ws = (int*)d_ws;

    // Only counters (+ overflow counter) need init (-1). Buckets are left
    // uninitialized: the gather's uniform tail-mask handles garbage entries.
    hipMemsetAsync((char*)d_ws + (size_t)CNT_OFF * 4, 0xFF,
                   (size_t)(NN + 1) * 4, stream);
    prep_fill_kernel<<<FILL_BLKS + PX_BLKS + PW_BLKS, 256, 0, stream>>>(
        x, eidx, ew, w1, w2, ws);
    gmlp_kernel<<<NN / 16, 256, 0, stream>>>(x, eidx, b1, b2, eps, ws, out);
}

// Round 4
// 204.461 us; speedup vs baseline: 1.1008x; 1.1008x over previous
//
#include <hip/hip_runtime.h>
#include <stdint.h>

#define NN 50000
#define NE 800000
#define D  128
#define CAP 64                            // bucket capacity per node (Poisson(16); P(deg>64)~1e-19)
#define OVF_CAP 131072

// ---------------- ws layout (int offsets) ----------------
// Counters init to -1 via 0xFF memset (slot = atomicAdd()+1). Buckets are
// UNINITIALIZED: gather masks tail entries to 0xFFFFFFFF (NaN weight, hot
// row 0xFFFF), and garbage src never escapes (mask applied at entry level).
#define CNT_OFF     64                    // NN counters
#define OVF_CNT_OFF (CNT_OFF + NN)        // 50064
#define OVF_OFF     (OVF_CNT_OFF + 4)     // 50068: OVF_CAP pairs (dst, entry)
#define BKT_OFF     312320                // NN*CAP packed entries: (w_fp16<<16)|src
#define XH_OFF      (BKT_OFF + NN * CAP)  // 3512320: x as fp16 pairs; 65536 logical rows
#define WH_OFF      (XH_OFF + 65536 * (D / 2))      // 7706624: w1+w2 fp16
// total high-water: 7,723,008 ints = 30.9 MB (< 32.4 MB proven available)

#define HSTRIDE 136                       // LDS row stride in ushorts (272 B, 2-way banks = free)

// fused prep+fill block ranges
#define FILL_BLKS 3125                    // NE/256 (1 edge/thread; R2-proven; atomic-throughput bound)
#define PX_BLKS   6250                    // NN*D/1024
#define PW_BLKS   32

typedef _Float16 half8 __attribute__((ext_vector_type(8)));
typedef __attribute__((ext_vector_type(4))) float float4v;

// ---------------- dtype helpers ----------------
__device__ __forceinline__ float b2f(uint16_t u) {
    union { uint32_t u; float f; } v; v.u = ((uint32_t)u) << 16; return v.f;
}
__device__ __forceinline__ uint16_t f2b(float f) {
    union { float f; uint32_t u; } v; v.f = f;
    uint32_t r = v.u + 0x7fffu + ((v.u >> 16) & 1u);   // RNE
    return (uint16_t)(r >> 16);
}
__device__ __forceinline__ ushort f2h(float f) {
    union { _Float16 h; ushort u; } v; v.h = (_Float16)f; return v.u;   // v_cvt_f16_f32 (RNE)
}
__device__ __forceinline__ float h2f(ushort u) {
    union { ushort u; _Float16 h; } v; v.u = u; return (float)v.h;
}

// ---------------- per-block inline dtype probe (load-bearing; rounds 2-9) ----------------
__device__ __forceinline__ void block_probe(const uint16_t* __restrict__ xraw,
                                            const int* __restrict__ eraw,
                                            int* sflags) {
    int t = threadIdx.x;
    if (t < 64) {                                   // wave 0 only
        float v0 = b2f(xraw[2 * t]);
        float v1 = b2f(xraw[2 * t + 1]);
        int bad = (!(v0 > -1e4f && v0 < 1e4f)) || (!(v1 > -1e4f && v1 < 1e4f));
        unsigned long long bm = __ballot(bad);
        int nz = (t < 32) ? (eraw[2 * t + 1] != 0) : 0;
        unsigned long long im = __ballot(nz);
        if (t == 0) { sflags[0] = bm ? 1 : 0; sflags[1] = im ? 0 : 1; }
    }
    __syncthreads();
}

// ---------------- fused fill + prep_x + prep_w ----------------
__global__ __launch_bounds__(256) void prep_fill_kernel(
    const uint16_t* __restrict__ xraw,
    const int*      __restrict__ eraw,
    const uint16_t* __restrict__ ewraw,
    const uint16_t* __restrict__ w1raw,
    const uint16_t* __restrict__ w2raw,
    int* __restrict__ ws)
{
    __shared__ int sflags[2];
    block_probe(xraw, eraw, sflags);
    const int f32 = sflags[0], i64 = sflags[1];

    int bid = blockIdx.x;
    if (bid < FILL_BLKS) {
        // ---- edge fill: one packed 4 B entry per edge ----
        int e = bid * 256 + threadIdx.x;
        int src, dst;
        if (i64) {
            const long long* e64 = (const long long*)eraw;
            src = (int)e64[e];
            dst = (int)e64[NE + e];
        } else {
            src = eraw[e];
            dst = eraw[NE + e];
        }
        if ((unsigned)src >= NN || (unsigned)dst >= NN) return;
        uint w = f32 ? (uint)f2h(((const float*)ewraw)[e]) : (uint)f2h(b2f(ewraw[e]));
        uint entry = (w << 16) | (uint)src;
        int slot = atomicAdd(ws + CNT_OFF + dst, 1) + 1;     // counter starts at -1
        if (slot < CAP) {
            ((uint*)(ws + BKT_OFF))[(size_t)dst * CAP + slot] = entry;
        } else {
            int o = atomicAdd(ws + OVF_CNT_OFF, 1) + 1;      // starts at -1
            if (o < OVF_CAP) {
                ws[OVF_OFF + 2 * o]     = dst;
                ws[OVF_OFF + 2 * o + 1] = (int)entry;
            }
        }
    } else if (bid < FILL_BLKS + PX_BLKS) {
        // ---- x -> fp16 table ----
        int i4 = ((bid - FILL_BLKS) * 256 + threadIdx.x) * 4;   // covers NN*D exactly
        ushort* dst = (ushort*)(ws + XH_OFF);
        if (f32) {
            float4 v = *(const float4*)((const float*)xraw + i4);
            ushort4 o; o.x = f2h(v.x); o.y = f2h(v.y); o.z = f2h(v.z); o.w = f2h(v.w);
            *(ushort4*)(dst + i4) = o;
        } else {
            ushort4 v = *(const ushort4*)(xraw + i4);
            ushort4 o; o.x = f2h(b2f(v.x)); o.y = f2h(b2f(v.y));
            o.z = f2h(b2f(v.z)); o.w = f2h(b2f(v.w));
            *(ushort4*)(dst + i4) = o;
        }
    } else {
        // ---- w1,w2 -> fp16 table ----
        int i4 = ((bid - FILL_BLKS - PX_BLKS) * 256 + threadIdx.x) * 4; // 0..32764
        const uint16_t* src = (i4 < 16384) ? w1raw : w2raw;
        int off = i4 & 16383;
        ushort* dst = (ushort*)(ws + WH_OFF);
        if (f32) {
            float4 v = *(const float4*)((const float*)src + off);
            ushort4 o; o.x = f2h(v.x); o.y = f2h(v.y); o.z = f2h(v.z); o.w = f2h(v.w);
            *(ushort4*)(dst + i4) = o;
        } else {
            ushort4 v = *(const ushort4*)(src + off);
            ushort4 o; o.x = f2h(b2f(v.x)); o.y = f2h(b2f(v.y));
            o.z = f2h(b2f(v.z)); o.w = f2h(b2f(v.w));
            *(ushort4*)(dst + i4) = o;
        }
    }
}

// ---------------- fused gather-max + MFMA MLP ----------------
// 16 nodes/block, 4 waves; wave gathers its 4 nodes serially (R2 structure,
// 44 VGPR proven) with ONE-step lookahead: node j+1's 16 bucket entries are
// prefetched into the same q[16] registers before node j's reduce/epilogue,
// hiding the entry-load latency under consume+reduce. Tail slots are masked
// to 0xFFFFFFFF at entry level: NaN weight (maxnum drops) + all tail gathers
// hit the single hot row 0xFFFF. __launch_bounds__(256,8) caps VGPR at 64
// (the R3 regression was the 64-VGPR occupancy cliff).
__global__ __launch_bounds__(256, 8) void gmlp_kernel(
    const uint16_t* __restrict__ xraw,
    const int*      __restrict__ eraw,
    const uint16_t* __restrict__ b1raw,
    const uint16_t* __restrict__ b2raw,
    const uint16_t* __restrict__ epsraw,
    const int* __restrict__ ws,
    uint16_t* __restrict__ outraw)
{
    __shared__ int    sflags[2];
    __shared__ uint   tl[16 * (HSTRIDE / 2)];   // t tile, 68 uints/row
    __shared__ ushort hl[16 * HSTRIDE];         // hidden tile

    block_probe(xraw, eraw, sflags);
    const int f32 = sflags[0];

    const int tid  = threadIdx.x;
    const int wave = tid >> 6;
    const int lane = tid & 63;
    const int m    = lane & 15;
    const int quad = lane >> 4;
    const int node0 = blockIdx.x * 16;

    const ushort* w1h = (const ushort*)(ws + WH_OFF);
    const ushort* w2h = w1h + 16384;
    const uint*   xh  = (const uint*)(ws + XH_OFF);
    const char*   xhb = (const char*)xh;
    const uint*   bkt = (const uint*)(ws + BKT_OFF);
    const uint    lane4 = (uint)lane * 4;

    const float eps1 = 1.0f + (f32 ? ((const float*)epsraw)[0] : b2f(epsraw[0]));

    // per-node degree loads (4 independent, hoisted)
    int deg[4], cnt[4];
    #pragma unroll
    for (int j = 0; j < 4; ++j)
        deg[j] = ws[CNT_OFF + node0 + wave * 4 + j] + 1;     // counter = deg-1
    #pragma unroll
    for (int j = 0; j < 4; ++j)
        cnt[j] = (deg[j] < CAP) ? deg[j] : CAP;

    const uint* wbase = bkt + (size_t)(node0 + wave * 4) * CAP;

    // prefetch node 0's first 16 entries
    uint q[16];
    #pragma unroll
    for (int q4 = 0; q4 < 4; ++q4)
        *(uint4*)&q[q4 * 4] = *(const uint4*)(wbase + q4 * 4);

    for (int j = 0; j < 4; ++j) {
        int nl = wave * 4 + j;
        int n  = node0 + nl;
        const uint* brow = wbase + j * CAP;

        uint mm[4];
        #pragma unroll
        for (int c = 0; c < 4; ++c) mm[c] = 0xFFFFFFFFu;     // packed fp16 NaN,NaN

        // step 0: entries already in q; mask tails at entry level
        if (cnt[j] > 0) {
            #pragma unroll
            for (int u = 0; u < 16; ++u) {
                uint e0 = (u < cnt[j]) ? q[u] : 0xffffffffu; // uniform sel; tail -> hot row + NaN w
                uint off = ((e0 & 0xffffu) << 8) + lane4;
                uint v   = *(const uint*)(xhb + off);
                uint p;
                asm("v_pk_mul_f16 %0, %1, %2 op_sel:[0,1] op_sel_hi:[1,1]"
                    : "=v"(p) : "v"(v), "v"(e0));            // both halves * hi16(e0)
                asm("v_pk_max_f16 %0, %0, %1" : "+v"(mm[u & 3]) : "v"(p));
            }
        }
        // steps >= 1 (deg > 16; ~40% of nodes take one extra step)
        for (int i = 16; i < cnt[j]; i += 16) {
            uint q2[16];
            #pragma unroll
            for (int q4 = 0; q4 < 4; ++q4)
                *(uint4*)&q2[q4 * 4] = *(const uint4*)(brow + i + q4 * 4);
            #pragma unroll
            for (int u = 0; u < 16; ++u) {
                uint e0 = ((i + u) < cnt[j]) ? q2[u] : 0xffffffffu;
                uint off = ((e0 & 0xffffu) << 8) + lane4;
                uint v   = *(const uint*)(xhb + off);
                uint p;
                asm("v_pk_mul_f16 %0, %1, %2 op_sel:[0,1] op_sel_hi:[1,1]"
                    : "=v"(p) : "v"(v), "v"(e0));
                asm("v_pk_max_f16 %0, %0, %1" : "+v"(mm[u & 3]) : "v"(p));
            }
        }

        // prefetch node j+1's first entries (overlaps with reduce/epilogue)
        if (j < 3) {
            const uint* nb = brow + CAP;
            #pragma unroll
            for (int q4 = 0; q4 < 4; ++q4)
                *(uint4*)&q[q4 * 4] = *(const uint4*)(nb + q4 * 4);
        }

        // reduce 4 -> 1
        asm("v_pk_max_f16 %0, %0, %1" : "+v"(mm[0]) : "v"(mm[1]));
        asm("v_pk_max_f16 %0, %0, %1" : "+v"(mm[2]) : "v"(mm[3]));
        asm("v_pk_max_f16 %0, %0, %1" : "+v"(mm[0]) : "v"(mm[2]));
        float mx = h2f((ushort)(mm[0] & 0xffffu));
        float my = h2f((ushort)(mm[0] >> 16));

        // overflow edges (exactness insurance; statistically never taken)
        if (deg[j] > CAP) {
            int novf = ws[OVF_CNT_OFF] + 1;
            if (novf > OVF_CAP) novf = OVF_CAP;
            for (int o = 0; o < novf; ++o) {
                if (ws[OVF_OFF + 2 * o] == n) {
                    uint e0 = (uint)ws[OVF_OFF + 2 * o + 1];
                    uint v  = xh[(e0 & 0xffffu) * 64 + lane];
                    float w = h2f((ushort)(e0 >> 16));
                    mx = fmaxf(mx, h2f((ushort)(v & 0xffffu)) * w);
                    my = fmaxf(my, h2f((ushort)(v >> 16)) * w);
                }
            }
        }
        if (deg[j] == 0) { mx = 0.f; my = 0.f; }             // isolated node -> 0

        // self term from fp16 table (cache-hot)
        uint xv = xh[(size_t)n * 64 + lane];
        float t0 = eps1 * h2f((ushort)(xv & 0xffffu)) + mx;
        float t1 = eps1 * h2f((ushort)(xv >> 16)) + my;
        tl[nl * (HSTRIDE / 2) + lane] = (uint)f2h(t0) | ((uint)f2h(t1) << 16);
    }
    __syncthreads();

    // A frags from LDS t tile
    half8 a[4];
    {
        const ushort* arow = (const ushort*)tl + m * HSTRIDE + quad * 8;
        #pragma unroll
        for (int kb = 0; kb < 4; ++kb) a[kb] = *(const half8*)(arow + kb * 32);
    }

    // GEMM1 + bias + LeakyReLU -> hl
    #pragma unroll
    for (int t = 0; t < 2; ++t) {
        int ct = wave * 2 + t;
        float4v c = {0.f, 0.f, 0.f, 0.f};
        const ushort* brow = w1h + (size_t)(ct * 16 + m) * 128 + quad * 8;
        #pragma unroll
        for (int kb = 0; kb < 4; ++kb)
            c = __builtin_amdgcn_mfma_f32_16x16x32_f16(a[kb], *(const half8*)(brow + kb * 32), c, 0, 0, 0);
        float bias = f32 ? ((const float*)b1raw)[ct * 16 + m] : b2f(b1raw[ct * 16 + m]);
        #pragma unroll
        for (int r = 0; r < 4; ++r) {
            float v = c[r] + bias;
            v = (v >= 0.f) ? v : 0.01f * v;
            hl[(quad * 4 + r) * HSTRIDE + ct * 16 + m] = f2h(v);
        }
    }
    __syncthreads();

    // A frags for GEMM2 from hl
    half8 ah[4];
    {
        const ushort* hrow = hl + m * HSTRIDE + quad * 8;
        #pragma unroll
        for (int kb = 0; kb < 4; ++kb) ah[kb] = *(const half8*)(hrow + kb * 32);
    }

    // GEMM2 + bias -> out
    #pragma unroll
    for (int t = 0; t < 2; ++t) {
        int ct = wave * 2 + t;
        float4v c = {0.f, 0.f, 0.f, 0.f};
        const ushort* brow = w2h + (size_t)(ct * 16 + m) * 128 + quad * 8;
        #pragma unroll
        for (int kb = 0; kb < 4; ++kb)
            c = __builtin_amdgcn_mfma_f32_16x16x32_f16(ah[kb], *(const half8*)(brow + kb * 32), c, 0, 0, 0);
        float bias = f32 ? ((const float*)b2raw)[ct * 16 + m] : b2f(b2raw[ct * 16 + m]);
        #pragma unroll
        for (int r = 0; r < 4; ++r) {
            float v = c[r] + bias;
            size_t o = (size_t)(node0 + quad * 4 + r) * 128 + ct * 16 + m;
            if (f32) ((float*)outraw)[o] = v;
            else     outraw[o] = f2b(v);
        }
    }
}

// ================= host =================
extern "C" void kernel_launch(void* const* d_in, const int* in_sizes, int n_in,
                              void* d_out, int out_size, void* d_ws, size_t ws_size,
                              hipStream_t stream) {
    const uint16_t* x    = (const uint16_t*)d_in[0];
    const int*      eidx = (const int*)     d_in[1];
    const uint16_t* ew   = (const uint16_t*)d_in[2];
    const uint16_t* w1   = (const uint16_t*)d_in[3];
    const uint16_t* b1   = (const uint16_t*)d_in[4];
    const uint16_t* w2   = (const uint16_t*)d_in[5];
    const uint16_t* b2   = (const uint16_t*)d_in[6];
    const uint16_t* eps  = (const uint16_t*)d_in[7];
    uint16_t*       out  = (uint16_t*)d_out;
    int* ws = (int*)d_ws;

    // Only counters (+ overflow counter) need init (-1). Buckets are left
    // uninitialized: the gather's entry-level tail-mask handles garbage.
    hipMemsetAsync((char*)d_ws + (size_t)CNT_OFF * 4, 0xFF,
                   (size_t)(NN + 1) * 4, stream);
    prep_fill_kernel<<<FILL_BLKS + PX_BLKS + PW_BLKS, 256, 0, stream>>>(
        x, eidx, ew, w1, w2, ws);
    gmlp_kernel<<<NN / 16, 256, 0, stream>>>(x, eidx, b1, b2, eps, ws, out);
}

// Round 5
// 196.161 us; speedup vs baseline: 1.1474x; 1.0423x over previous
//
#include <hip/hip_runtime.h>
#include <stdint.h>

#define NN 50000
#define NE 800000
#define D  128
#define CAP 64                            // bucket capacity per node (Poisson(16); P(deg>64)~1e-19)
#define OVF_CAP 131072

// ---------------- ws layout (int offsets) ----------------
// Counters init to -1 via 0xFF memset (slot = atomicAdd()+1). Buckets are
// UNINITIALIZED: gather masks tail entries to 0xFFFFFFFF (NaN weight, hot
// row 0xFFFF), and garbage src never escapes (mask applied at entry level).
#define CNT_OFF     64                    // NN counters
#define OVF_CNT_OFF (CNT_OFF + NN)        // 50064
#define OVF_OFF     (OVF_CNT_OFF + 4)     // 50068: OVF_CAP pairs (dst, entry)
#define BKT_OFF     312320                // NN*CAP packed entries: (w_fp16<<16)|src
#define XH_OFF      (BKT_OFF + NN * CAP)  // 3512320: x as fp16 pairs; 65536 logical rows
#define WH_OFF      (XH_OFF + 65536 * (D / 2))      // 7706624: w1+w2 fp16
// total high-water: 7,723,008 ints = 30.9 MB (< 32.4 MB proven available)

#define HSTRIDE 136                       // LDS row stride in ushorts (272 B, 2-way banks = free)
#define SLOTS   24                        // staged row-gathers per node (fixed, unrolled)
#define WLDS    (SLOTS * 256 + 1024)      // per-wave LDS: 24 value rows + 4 bucket rows

// fused prep+fill block ranges
#define FILL_BLKS 3125                    // NE/256 (1 edge/thread; atomic-throughput bound)
#define PX_BLKS   6250                    // NN*D/1024
#define PW_BLKS   32

typedef _Float16 half8 __attribute__((ext_vector_type(8)));
typedef __attribute__((ext_vector_type(4))) float float4v;

// ---------------- dtype helpers ----------------
__device__ __forceinline__ float b2f(uint16_t u) {
    union { uint32_t u; float f; } v; v.u = ((uint32_t)u) << 16; return v.f;
}
__device__ __forceinline__ uint16_t f2b(float f) {
    union { float f; uint32_t u; } v; v.f = f;
    uint32_t r = v.u + 0x7fffu + ((v.u >> 16) & 1u);   // RNE
    return (uint16_t)(r >> 16);
}
__device__ __forceinline__ ushort f2h(float f) {
    union { _Float16 h; ushort u; } v; v.h = (_Float16)f; return v.u;   // v_cvt_f16_f32 (RNE)
}
__device__ __forceinline__ float h2f(ushort u) {
    union { ushort u; _Float16 h; } v; v.u = u; return (float)v.h;
}

// async global->LDS, 4 B per lane: LDS dest = uniform base + lane*4,
// global src = per-lane address. Counts in vmcnt.
__device__ __forceinline__ void gload_lds4(const void* g, void* l) {
    __builtin_amdgcn_global_load_lds(
        (const __attribute__((address_space(1))) void*)g,
        (__attribute__((address_space(3))) void*)l, 4, 0, 0);
}

// ---------------- per-block inline dtype probe (load-bearing; rounds 2-9) ----------------
__device__ __forceinline__ void block_probe(const uint16_t* __restrict__ xraw,
                                            const int* __restrict__ eraw,
                                            int* sflags) {
    int t = threadIdx.x;
    if (t < 64) {                                   // wave 0 only
        float v0 = b2f(xraw[2 * t]);
        float v1 = b2f(xraw[2 * t + 1]);
        int bad = (!(v0 > -1e4f && v0 < 1e4f)) || (!(v1 > -1e4f && v1 < 1e4f));
        unsigned long long bm = __ballot(bad);
        int nz = (t < 32) ? (eraw[2 * t + 1] != 0) : 0;
        unsigned long long im = __ballot(nz);
        if (t == 0) { sflags[0] = bm ? 1 : 0; sflags[1] = im ? 0 : 1; }
    }
    __syncthreads();
}

// ---------------- fused fill + prep_x + prep_w (unchanged; ±10% noise band) ----------------
__global__ __launch_bounds__(256) void prep_fill_kernel(
    const uint16_t* __restrict__ xraw,
    const int*      __restrict__ eraw,
    const uint16_t* __restrict__ ewraw,
    const uint16_t* __restrict__ w1raw,
    const uint16_t* __restrict__ w2raw,
    int* __restrict__ ws)
{
    __shared__ int sflags[2];
    block_probe(xraw, eraw, sflags);
    const int f32 = sflags[0], i64 = sflags[1];

    int bid = blockIdx.x;
    if (bid < FILL_BLKS) {
        // ---- edge fill: one packed 4 B entry per edge ----
        int e = bid * 256 + threadIdx.x;
        int src, dst;
        if (i64) {
            const long long* e64 = (const long long*)eraw;
            src = (int)e64[e];
            dst = (int)e64[NE + e];
        } else {
            src = eraw[e];
            dst = eraw[NE + e];
        }
        if ((unsigned)src >= NN || (unsigned)dst >= NN) return;
        uint w = f32 ? (uint)f2h(((const float*)ewraw)[e]) : (uint)f2h(b2f(ewraw[e]));
        uint entry = (w << 16) | (uint)src;
        int slot = atomicAdd(ws + CNT_OFF + dst, 1) + 1;     // counter starts at -1
        if (slot < CAP) {
            ((uint*)(ws + BKT_OFF))[(size_t)dst * CAP + slot] = entry;
        } else {
            int o = atomicAdd(ws + OVF_CNT_OFF, 1) + 1;      // starts at -1
            if (o < OVF_CAP) {
                ws[OVF_OFF + 2 * o]     = dst;
                ws[OVF_OFF + 2 * o + 1] = (int)entry;
            }
        }
    } else if (bid < FILL_BLKS + PX_BLKS) {
        // ---- x -> fp16 table ----
        int i4 = ((bid - FILL_BLKS) * 256 + threadIdx.x) * 4;   // covers NN*D exactly
        ushort* dst = (ushort*)(ws + XH_OFF);
        if (f32) {
            float4 v = *(const float4*)((const float*)xraw + i4);
            ushort4 o; o.x = f2h(v.x); o.y = f2h(v.y); o.z = f2h(v.z); o.w = f2h(v.w);
            *(ushort4*)(dst + i4) = o;
        } else {
            ushort4 v = *(const ushort4*)(xraw + i4);
            ushort4 o; o.x = f2h(b2f(v.x)); o.y = f2h(b2f(v.y));
            o.z = f2h(b2f(v.z)); o.w = f2h(b2f(v.w));
            *(ushort4*)(dst + i4) = o;
        }
    } else {
        // ---- w1,w2 -> fp16 table ----
        int i4 = ((bid - FILL_BLKS - PX_BLKS) * 256 + threadIdx.x) * 4; // 0..32764
        const uint16_t* src = (i4 < 16384) ? w1raw : w2raw;
        int off = i4 & 16383;
        ushort* dst = (ushort*)(ws + WH_OFF);
        if (f32) {
            float4 v = *(const float4*)((const float*)src + off);
            ushort4 o; o.x = f2h(v.x); o.y = f2h(v.y); o.z = f2h(v.z); o.w = f2h(v.w);
            *(ushort4*)(dst + i4) = o;
        } else {
            ushort4 v = *(const ushort4*)(src + off);
            ushort4 o; o.x = f2h(b2f(v.x)); o.y = f2h(b2f(v.y));
            o.z = f2h(b2f(v.z)); o.w = f2h(b2f(v.w));
            *(ushort4*)(dst + i4) = o;
        }
    }
}

// ---------------- fused gather-max + MFMA MLP ----------------
// 16 nodes/block, 4 waves. Gather uses global_load_lds so outstanding row
// fetches cost LDS, not VGPRs (the R3 lesson): per node, a FIXED fully-
// unrolled 24-slot staged pass (tails NaN-masked to hot row 0xFFFF) ->
// s_waitcnt vmcnt(0) -> consume from LDS with packed fp16 mul/max.
// Bucket entry rows (4x256B/wave) are also LDS-staged once at kernel start.
// deg>24 remainder (~2% of nodes) takes a serial per-edge loop; deg>64
// overflow path unchanged. hl overlays the gather buffer post-sync.
__global__ __launch_bounds__(256, 4) void gmlp_kernel(
    const uint16_t* __restrict__ xraw,
    const int*      __restrict__ eraw,
    const uint16_t* __restrict__ b1raw,
    const uint16_t* __restrict__ b2raw,
    const uint16_t* __restrict__ epsraw,
    const int* __restrict__ ws,
    uint16_t* __restrict__ outraw)
{
    __shared__ char smem[4][WLDS];              // per-wave: [0,6144) value rows, [6144,7168) bucket rows
    __shared__ uint tl[16 * (HSTRIDE / 2)];     // t tile, 68 uints/row
    __shared__ int  sflags[2];
    ushort* hl = (ushort*)&smem[0][0];          // hidden tile overlay (post-sync)

    const int tid  = threadIdx.x;
    const int wave = tid >> 6;
    const int lane = tid & 63;
    const int m    = lane & 15;
    const int quad = lane >> 4;
    const int node0 = blockIdx.x * 16;

    const ushort* w1h = (const ushort*)(ws + WH_OFF);
    const ushort* w2h = w1h + 16384;
    const uint*   xh  = (const uint*)(ws + XH_OFF);
    const char*   xhb = (const char*)xh;
    const uint*   bkt = (const uint*)(ws + BKT_OFF);
    const uint    lane4 = (uint)lane * 4;
    char*         wbuf  = smem[wave];

    // stage the wave's 4 bucket rows into LDS (async, counts in vmcnt)
    #pragma unroll
    for (int j = 0; j < 4; ++j)
        gload_lds4(bkt + (size_t)(node0 + wave * 4 + j) * CAP + lane,
                   wbuf + SLOTS * 256 + j * 256);

    // per-node degree + self-row prefetch (independent loads)
    int deg[4];
    uint xv[4];
    #pragma unroll
    for (int j = 0; j < 4; ++j) {
        deg[j] = ws[CNT_OFF + node0 + wave * 4 + j] + 1;     // counter = deg-1
        xv[j]  = xh[(size_t)(node0 + wave * 4 + j) * 64 + lane];
    }

    block_probe(xraw, eraw, sflags);
    const int f32 = sflags[0];
    const float eps1 = 1.0f + (f32 ? ((const float*)epsraw)[0] : b2f(epsraw[0]));

    asm volatile("s_waitcnt vmcnt(0)" ::: "memory");         // bucket rows in LDS

    #pragma unroll
    for (int j = 0; j < 4; ++j) {
        int nl = wave * 4 + j;
        int n  = node0 + nl;
        int cnt = (deg[j] < CAP) ? deg[j] : CAP;
        const uint* ewp = (const uint*)(wbuf + SLOTS * 256 + j * 256);

        // prior node's ds_reads must be done before DMA re-writes the slots
        asm volatile("s_waitcnt lgkmcnt(0)" ::: "memory");

        // issue: fixed 24 staged row-gathers (tails -> hot row, NaN weight)
        uint eq[SLOTS];
        #pragma unroll
        for (int g = 0; g < SLOTS / 4; ++g) {
            uint4 e4 = *(const uint4*)(ewp + g * 4);
            #pragma unroll
            for (int t = 0; t < 4; ++t) {
                int u = g * 4 + t;
                uint e0 = (u < cnt) ? ((const uint*)&e4)[t] : 0xffffffffu;
                eq[u] = e0;
                gload_lds4(xhb + ((e0 & 0xffffu) << 8) + lane4, wbuf + u * 256);
            }
        }
        asm volatile("s_waitcnt vmcnt(0)" ::: "memory");     // value rows in LDS

        // consume: packed fp16 mul/max, 2-way-free LDS reads
        uint mm[4] = {~0u, ~0u, ~0u, ~0u};                   // fp16 NaN,NaN
        #pragma unroll
        for (int u = 0; u < SLOTS; ++u) {
            uint v = *(const uint*)(wbuf + u * 256 + lane4);
            uint p;
            asm("v_pk_mul_f16 %0, %1, %2 op_sel:[0,1] op_sel_hi:[1,1]"
                : "=v"(p) : "v"(v), "v"(eq[u]));             // both halves * hi16(entry)
            asm("v_pk_max_f16 %0, %0, %1" : "+v"(mm[u & 3]) : "v"(p));
        }
        // remainder edges 24..cnt (P(deg>24) ~ 2%): serial, direct from global
        for (int i = SLOTS; i < cnt; ++i) {
            uint e0 = ewp[i];
            uint v  = *(const uint*)(xhb + ((e0 & 0xffffu) << 8) + lane4);
            uint p;
            asm("v_pk_mul_f16 %0, %1, %2 op_sel:[0,1] op_sel_hi:[1,1]"
                : "=v"(p) : "v"(v), "v"(e0));
            asm("v_pk_max_f16 %0, %0, %1" : "+v"(mm[0]) : "v"(p));
        }

        // reduce 4 -> 1
        asm("v_pk_max_f16 %0, %0, %1" : "+v"(mm[0]) : "v"(mm[1]));
        asm("v_pk_max_f16 %0, %0, %1" : "+v"(mm[2]) : "v"(mm[3]));
        asm("v_pk_max_f16 %0, %0, %1" : "+v"(mm[0]) : "v"(mm[2]));
        float mx = h2f((ushort)(mm[0] & 0xffffu));
        float my = h2f((ushort)(mm[0] >> 16));

        // overflow edges (exactness insurance; statistically never taken)
        if (deg[j] > CAP) {
            int novf = ws[OVF_CNT_OFF] + 1;
            if (novf > OVF_CAP) novf = OVF_CAP;
            for (int o = 0; o < novf; ++o) {
                if (ws[OVF_OFF + 2 * o] == n) {
                    uint e0 = (uint)ws[OVF_OFF + 2 * o + 1];
                    uint v  = xh[(e0 & 0xffffu) * 64 + lane];
                    float w = h2f((ushort)(e0 >> 16));
                    mx = fmaxf(mx, h2f((ushort)(v & 0xffffu)) * w);
                    my = fmaxf(my, h2f((ushort)(v >> 16)) * w);
                }
            }
        }
        if (deg[j] == 0) { mx = 0.f; my = 0.f; }             // isolated node -> 0

        // self term from prefetched row
        float t0 = eps1 * h2f((ushort)(xv[j] & 0xffffu)) + mx;
        float t1 = eps1 * h2f((ushort)(xv[j] >> 16)) + my;
        tl[nl * (HSTRIDE / 2) + lane] = (uint)f2h(t0) | ((uint)f2h(t1) << 16);
    }
    __syncthreads();

    // A frags from LDS t tile
    half8 a[4];
    {
        const ushort* arow = (const ushort*)tl + m * HSTRIDE + quad * 8;
        #pragma unroll
        for (int kb = 0; kb < 4; ++kb) a[kb] = *(const half8*)(arow + kb * 32);
    }

    // GEMM1 + bias + LeakyReLU -> hl (overlaid on gather buffer)
    #pragma unroll
    for (int t = 0; t < 2; ++t) {
        int ct = wave * 2 + t;
        float4v c = {0.f, 0.f, 0.f, 0.f};
        const ushort* brow = w1h + (size_t)(ct * 16 + m) * 128 + quad * 8;
        #pragma unroll
        for (int kb = 0; kb < 4; ++kb)
            c = __builtin_amdgcn_mfma_f32_16x16x32_f16(a[kb], *(const half8*)(brow + kb * 32), c, 0, 0, 0);
        float bias = f32 ? ((const float*)b1raw)[ct * 16 + m] : b2f(b1raw[ct * 16 + m]);
        #pragma unroll
        for (int r = 0; r < 4; ++r) {
            float v = c[r] + bias;
            v = (v >= 0.f) ? v : 0.01f * v;
            hl[(quad * 4 + r) * HSTRIDE + ct * 16 + m] = f2h(v);
        }
    }
    __syncthreads();

    // A frags for GEMM2 from hl
    half8 ah[4];
    {
        const ushort* hrow = hl + m * HSTRIDE + quad * 8;
        #pragma unroll
        for (int kb = 0; kb < 4; ++kb) ah[kb] = *(const half8*)(hrow + kb * 32);
    }

    // GEMM2 + bias -> out
    #pragma unroll
    for (int t = 0; t < 2; ++t) {
        int ct = wave * 2 + t;
        float4v c = {0.f, 0.f, 0.f, 0.f};
        const ushort* brow = w2h + (size_t)(ct * 16 + m) * 128 + quad * 8;
        #pragma unroll
        for (int kb = 0; kb < 4; ++kb)
            c = __builtin_amdgcn_mfma_f32_16x16x32_f16(ah[kb], *(const half8*)(brow + kb * 32), c, 0, 0, 0);
        float bias = f32 ? ((const float*)b2raw)[ct * 16 + m] : b2f(b2raw[ct * 16 + m]);
        #pragma unroll
        for (int r = 0; r < 4; ++r) {
            float v = c[r] + bias;
            size_t o = (size_t)(node0 + quad * 4 + r) * 128 + ct * 16 + m;
            if (f32) ((float*)outraw)[o] = v;
            else     outraw[o] = f2b(v);
        }
    }
}

// ================= host =================
extern "C" void kernel_launch(void* const* d_in, const int* in_sizes, int n_in,
                              void* d_out, int out_size, void* d_ws, size_t ws_size,
                              hipStream_t stream) {
    const uint16_t* x    = (const uint16_t*)d_in[0];
    const int*      eidx = (const int*)     d_in[1];
    const uint16_t* ew   = (const uint16_t*)d_in[2];
    const uint16_t* w1   = (const uint16_t*)d_in[3];
    const uint16_t* b1   = (const uint16_t*)d_in[4];
    const uint16_t* w2   = (const uint16_t*)d_in[5];
    const uint16_t* b2   = (const uint16_t*)d_in[6];
    const uint16_t* eps  = (const uint16_t*)d_in[7];
    uint16_t*       out  = (uint16_t*)d_out;
    int* ws = (int*)d_ws;

    // Only counters (+ overflow counter) need init (-1). Buckets are left
    // uninitialized: the gather's entry-level tail-mask handles garbage.
    hipMemsetAsync((char*)d_ws + (size_t)CNT_OFF * 4, 0xFF,
                   (size_t)(NN + 1) * 4, stream);
    prep_fill_kernel<<<FILL_BLKS + PX_BLKS + PW_BLKS, 256, 0, stream>>>(
        x, eidx, ew, w1, w2, ws);
    gmlp_kernel<<<NN / 16, 256, 0, stream>>>(x, eidx, b1, b2, eps, ws, out);
}